// Round 9
// baseline (2853.763 us; speedup 1.0000x reference)
//
#include <hip/hip_runtime.h>
#include <math.h>

#define Tt 4096
#define NB 16

#define CLN2PI 1.8378770664093453f   // ln(2*pi)

// ws layout (float offsets)
#define OFF_W    0         // 131072  W = L^-1 per state (row-major, upper zeros)
#define OFF_D    131072    // 2048    d = W*mu
#define OFF_CST  133120    // 32      F*ln2pi + logdet  (nats)
#define OFF_EV   133152    // 16      evidence per batch (fp32 nats)
#define OFF_LB   133184    // 2097152 logB nats [b][t][s]
#define OFF_BET  2230336   // 2097152 beta  nats [b][t][s]
// total 4327488 floats = 17.3 MB

__device__ __forceinline__ float rdlane(float x, int l) {
  return __int_as_float(__builtin_amdgcn_readlane(__float_as_int(x), l));
}
__device__ __forceinline__ float bpermf(int idx, float x) {
  return __int_as_float(__builtin_amdgcn_ds_bpermute(idx, __float_as_int(x)));
}

// ---------------- K2: per-state Cholesky, W = L^-1, d = W*mu, cst ----------------
__global__ __launch_bounds__(64) void k_chol(const float* __restrict__ covs,
                                             const float* __restrict__ means,
                                             float* __restrict__ ws) {
  __shared__ float Am[64][65];
  __shared__ float Wl[64][65];
  int s = blockIdx.x, j = threadIdx.x;
  for (int r = 0; r < 64; ++r) {
    Am[r][j] = covs[((size_t)s * 64 + r) * 64 + j];
    Wl[r][j] = 0.f;
  }
  __syncthreads();
  for (int k = 0; k < 64; ++k) {
    float diag = sqrtf(Am[k][k]);
    float col = (j > k) ? Am[j][k] / diag : 0.f;
    __syncthreads();
    if (j == k) Am[k][k] = diag;
    if (j > k)  Am[j][k] = col;
    __syncthreads();
    if (j > k) {
      for (int g = k + 1; g <= j; ++g) Am[j][g] -= col * Am[g][k];
    }
    __syncthreads();
  }
  {
    int c = j;
    Wl[c][c] = 1.0f / Am[c][c];
    for (int f = c + 1; f < 64; ++f) {
      float ssum = 0.f;
      for (int g = c; g < f; ++g) ssum += Am[f][g] * Wl[g][c];
      Wl[f][c] = -ssum / Am[f][f];
    }
  }
  __syncthreads();
  for (int r = 0; r < 64; ++r)
    ws[OFF_W + ((size_t)s * 64 + r) * 64 + j] = Wl[r][j];
  {
    float acc = 0.f;
    for (int g = 0; g < 64; ++g) acc += Wl[j][g] * means[s * 64 + g];
    ws[OFF_D + s * 64 + j] = acc;
  }
  if (j == 0) {
    float logdet = 0.f;
    for (int k = 0; k < 64; ++k) logdet += __logf(Am[k][k]);
    logdet *= 2.0f;
    ws[OFF_CST + s] = 64.0f * CLN2PI + logdet;
  }
}

// ---------------- K3: emission logB (nats) ----------------
__global__ __launch_bounds__(64) void k_emis(const float* __restrict__ x,
                                             const float* __restrict__ wsr,
                                             float* __restrict__ lb) {
  const float* W = wsr + OFF_W;
  const float* D = wsr + OFF_D;
  const float* C = wsr + OFF_CST;
  int bx = blockIdx.x;
  int sgrp = bx & 3;
  int pt = (bx >> 2) * 64 + threadIdx.x;
  const float* xr = x + (size_t)pt * 64;
  float xv[64];
#pragma unroll
  for (int c = 0; c < 16; ++c) {
    float4 q = ((const float4*)xr)[c];
    xv[4 * c + 0] = q.x; xv[4 * c + 1] = q.y;
    xv[4 * c + 2] = q.z; xv[4 * c + 3] = q.w;
  }
#pragma unroll 1
  for (int si = 0; si < 8; ++si) {
    int s = sgrp * 8 + si;
    const float* Ws = W + (size_t)s * 4096;
    const float* Ds = D + s * 64;
    float maha = 0.f;
#pragma unroll
    for (int f = 0; f < 64; ++f) {
      float z = -Ds[f];
#pragma unroll
      for (int ch = 0; ch < 4; ++ch) {
        if (ch <= (f >> 4)) {
#pragma unroll
          for (int gg = 0; gg < 16; ++gg) {
            int g = ch * 16 + gg;
            z = fmaf(Ws[f * 64 + g], xv[g], z);
          }
        }
      }
      maha = fmaf(z, z, maha);
    }
    lb[(size_t)pt * 32 + s] = -0.5f * (maha + C[s]);
  }
}

// np-pairwise-order sum of 32 (epilogue use)
__device__ __forceinline__ float npsum32(const float* z) {
  float r[8];
#pragma unroll
  for (int k = 0; k < 8; ++k)
    r[k] = ((z[k] + z[k + 8]) + z[k + 16]) + z[k + 24];
  return ((r[0] + r[1]) + (r[2] + r[3])) + ((r[4] + r[5]) + (r[6] + r[7]));
}
__device__ __forceinline__ float max32(const float* z) {
  float t16[16];
#pragma unroll
  for (int k = 0; k < 16; ++k) t16[k] = fmaxf(z[k], z[k + 16]);
  float t8[8];
#pragma unroll
  for (int k = 0; k < 8; ++k) t8[k] = fmaxf(t16[k], t16[k + 8]);
  float t4[4];
#pragma unroll
  for (int k = 0; k < 4; ++k) t4[k] = fmaxf(t8[k], t8[k + 4]);
  return fmaxf(fmaxf(t4[0], t4[2]), fmaxf(t4[1], t4[3]));
}
// max of 16 local values (exact, order-free)
__device__ __forceinline__ float max16(const float* z) {
  float t8[8];
#pragma unroll
  for (int k = 0; k < 8; ++k) t8[k] = fmaxf(z[k], z[k + 8]);
  float t4[4];
#pragma unroll
  for (int k = 0; k < 4; ++k) t4[k] = fmaxf(t8[k], t8[k + 4]);
  return fmaxf(fmaxf(t4[0], t4[2]), fmaxf(t4[1], t4[3]));
}

// ---------------- K4: forward/backward, half-split i-range ----------------
// NUMERICS FROZEN (R2/R5/R7): z_i = fl(a_i + A_ij), per-column max (exact,
// any tree), Sterbenz-exact sub in nat domain, __expf, numpy pairwise-8 sum
// order ((e[k]+e[k+8])+e[k+16])+e[k+24], a = ((logf(S)+m)+lb).
// Structure: lanes (j, j+32) co-own column j. half h computes i = 16h+k.
// Cross-half via ds_bpermute: a-broadcast (16), max exchange (1),
// e-transfer (16). Half1's post-sum values are garbage; stores are masked
// to lanes 0-31. Per-lane per-step: 16 exps (was 32), 16 z-adds (was 32).
__global__ __launch_bounds__(64, 1)
void k_fb(const float* logA,
          const float* logpi,
          float* ws,
          float* out) {
  const float* lbg = ws + OFF_LB;
  float* bet = ws + OFF_BET;
  float* ev  = ws + OFF_EV;
  int chain = blockIdx.x;
  int b   = chain & 15;
  int dir = chain >> 4;
  int lane = threadIdx.x;
  int j = lane & 31;
  int h = lane >> 5;                    // i-half this lane computes
  int idxx = (lane ^ 32) << 2;          // cross-half bpermute index
  int idxb = h << 6;                    // a-broadcast base: (h*16)*4
  const float* lb = lbg + (size_t)b * Tt * 32;
  float z[16], e[16], er[16];
  if (dir == 0) {
    float areg[16];                      // A[16h+k][j]
#pragma unroll
    for (int k = 0; k < 16; ++k) areg[k] = logA[(h * 16 + k) * 32 + j];
    float* ao = out + (size_t)b * Tt * 32;
    float a = logpi[j] + lb[j];          // alpha[0] (valid in both halves)
    if (lane < 32) ao[j] = a;
    float bA = lb[32 + j];
    float bB = lb[64 + j];
    float bC = lb[96 + j];
    float bD = lb[128 + j];
#pragma unroll 1
    for (int t = 1; t < Tt; ++t) {
      float bcur = bA; bA = bB; bB = bC; bC = bD;
      if (t + 4 < Tt) bD = lb[(size_t)(t + 4) * 32 + j];
      // broadcast a_i (i = 16h+k) from half0 lanes
#pragma unroll
      for (int k = 0; k < 16; ++k)
        z[k] = bpermf(idxb + (k << 2), a) + areg[k];  // fl(a_i + A[i][j])
      float p = max16(z);
      float m = fmaxf(p, bpermf(idxx, p));            // global column max
#pragma unroll
      for (int k = 0; k < 16; ++k) e[k] = __expf(z[k] - m);  // exact sub
#pragma unroll
      for (int k = 0; k < 16; ++k) er[k] = bpermf(idxx, e[k]);
      // half0: e[] = e_np[0..15], er[] = e_np[16..31]; numpy pairwise-8:
      float r[8];
#pragma unroll
      for (int k = 0; k < 8; ++k)
        r[k] = ((e[k] + e[k + 8]) + er[k]) + er[k + 8];
      float S = ((r[0] + r[1]) + (r[2] + r[3])) + ((r[4] + r[5]) + (r[6] + r[7]));
      a = (__logf(S) + m) + bcur;        // valid in half0 only
      if (lane < 32) ao[(size_t)t * 32 + j] = a;
    }
    // evidence = logsumexp(alpha[T-1]) — np-exact, from half0's a
    float z2[32];
#pragma unroll
    for (int i = 0; i < 32; ++i) z2[i] = rdlane(a, i);
    float m = max32(z2);
#pragma unroll
    for (int i = 0; i < 32; ++i) z2[i] = __expf(z2[i] - m);
    float S = npsum32(z2);
    if (lane == 0) ev[b] = __logf(S) + m;
  } else {
    float areg[16];                      // A[j][16h+k]
#pragma unroll
    for (int k = 0; k < 16; ++k) areg[k] = logA[j * 32 + h * 16 + k];
    float* bo = bet + (size_t)b * Tt * 32;
    if (lane < 32) bo[(size_t)(Tt - 1) * 32 + j] = 0.f;
    float y = lb[(size_t)(Tt - 1) * 32 + j] + 0.f;   // (logB[T-1] + beta[T-1])
    float bA = lb[(size_t)(Tt - 2) * 32 + j];
    float bB = lb[(size_t)(Tt - 3) * 32 + j];
    float bC = lb[(size_t)(Tt - 4) * 32 + j];
    float bD = lb[(size_t)(Tt - 5) * 32 + j];
#pragma unroll 1
    for (int t = Tt - 2; t >= 0; --t) {
      float bcur = bA; bA = bB; bB = bC; bC = bD;
      if (t >= 4) bD = lb[(size_t)(t - 4) * 32 + j];
#pragma unroll
      for (int k = 0; k < 16; ++k)
        z[k] = areg[k] + bpermf(idxb + (k << 2), y);  // fl(A[j][i] + y_i)
      float p = max16(z);
      float m = fmaxf(p, bpermf(idxx, p));
#pragma unroll
      for (int k = 0; k < 16; ++k) e[k] = __expf(z[k] - m);
#pragma unroll
      for (int k = 0; k < 16; ++k) er[k] = bpermf(idxx, e[k]);
      float r[8];
#pragma unroll
      for (int k = 0; k < 8; ++k)
        r[k] = ((e[k] + e[k + 8]) + er[k]) + er[k + 8];
      float S = ((r[0] + r[1]) + (r[2] + r[3])) + ((r[4] + r[5]) + (r[6] + r[7]));
      float bv = __logf(S) + m;          // beta[t][j], valid in half0
      if (lane < 32) bo[(size_t)t * 32 + j] = bv;
      y = bcur + bv;                     // (logB[t] + beta[t]); half1 garbage,
                                         // never read (broadcast pulls half0)
    }
  }
}

// ---------------- K5: gamma = (alpha + beta) - evidence, fp32 ----------------
__global__ void k_gamma(const float* __restrict__ ws, float* __restrict__ out) {
  size_t idx = (size_t)blockIdx.x * blockDim.x + threadIdx.x;
  if (idx >= (size_t)NB * Tt * 32) return;
  int b = (int)(idx >> 17);            // T*S = 131072
  float a  = out[idx];
  float bb = ws[OFF_BET + idx];
  float e  = ws[OFF_EV + b];
  out[idx] = (a + bb) - e;
}

extern "C" void kernel_launch(void* const* d_in, const int* in_sizes, int n_in,
                              void* d_out, int out_size, void* d_ws, size_t ws_size,
                              hipStream_t stream) {
  const float* x     = (const float*)d_in[0];
  const float* means = (const float*)d_in[1];
  const float* covs  = (const float*)d_in[2];
  const float* logA  = (const float*)d_in[3];
  const float* logpi = (const float*)d_in[4];
  float* ws  = (float*)d_ws;
  float* out = (float*)d_out;

  k_chol<<<dim3(32), dim3(64), 0, stream>>>(covs, means, ws);
  k_emis<<<dim3(4096), dim3(64), 0, stream>>>(x, ws, ws + OFF_LB);
  k_fb<<<dim3(32), dim3(64), 0, stream>>>(logA, logpi, ws, out);
  k_gamma<<<dim3(8192), dim3(256), 0, stream>>>(ws, out);
}